// Round 5
// baseline (935.248 us; speedup 1.0000x reference)
//
#include <hip/hip_runtime.h>
#include <stdint.h>

#pragma clang fp contract(off)

#define NB   8
#define NM   1024
#define NGT  100

typedef uint32_t u32;
typedef unsigned long long u64;

// ---------- Threefry-2x32 block (exact JAX schedule) ----------
__device__ __forceinline__ void tf2x32(u32 k0, u32 k1, u32 x0, u32 x1, u32& o0, u32& o1) {
    u32 k2 = k0 ^ k1 ^ 0x1BD11BDAu;
#define TFR(r) { x0 += x1; x1 = (x1 << r) | (x1 >> (32 - r)); x1 ^= x0; }
    x0 += k0; x1 += k1;
    TFR(13) TFR(15) TFR(26) TFR(6)
    x0 += k1; x1 += k2 + 1u;
    TFR(17) TFR(29) TFR(16) TFR(24)
    x0 += k2; x1 += k0 + 2u;
    TFR(13) TFR(15) TFR(26) TFR(6)
    x0 += k0; x1 += k1 + 3u;
    TFR(17) TFR(29) TFR(16) TFR(24)
    x0 += k1; x1 += k2 + 4u;
    TFR(13) TFR(15) TFR(26) TFR(6)
    x0 += k2; x1 += k0 + 5u;
#undef TFR
    o0 = x0; o1 = x1;
}

// JAX partitionable threefry: split(key,n)[i] = (o0,o1) at x=(0,i);
// random_bits(key,32,(n,))[i] = o0 ^ o1 at x=(0,i)
__device__ __forceinline__ u32 tf_bits32(u32 k0, u32 k1, u32 i) {
    u32 o0, o1;
    tf2x32(k0, k1, 0u, i, o0, o1);
    return o0 ^ o1;
}

__device__ __forceinline__ float bits2unif(u32 bits) {
    return __uint_as_float((bits >> 9) | 0x3f800000u) - 1.0f;
}

__device__ __forceinline__ void image_keys(int b, u32 k[4][2]) {
    u32 kb0, kb1;
    tf2x32(0u, 42u, 0u, (u32)b, kb0, kb1);           // split(key(42), 8)[b]
    for (int i = 0; i < 4; i++)
        tf2x32(kb0, kb1, 0u, (u32)i, k[i][0], k[i][1]);  // split(key_b, 4)[i]
}

__device__ __forceinline__ float unif_at(const u32 k[2], int i) {
    return bits2unif(tf_bits32(k[0], k[1], (u32)i));
}

// ---------- numpy pairwise blocked sum over exactly 24 f32 terms ----------
// (numpy: r[j]=a[j]; r[j]+=a[8+j]; r[j]+=a[16+j]; then ((r0+r1)+(r2+r3))+((r4+r5)+(r6+r7)))
__device__ __forceinline__ float np_pw24(const float* t) {
    float r0 = (t[0] + t[8])  + t[16];
    float r1 = (t[1] + t[9])  + t[17];
    float r2 = (t[2] + t[10]) + t[18];
    float r3 = (t[3] + t[11]) + t[19];
    float r4 = (t[4] + t[12]) + t[20];
    float r5 = (t[5] + t[13]) + t[21];
    float r6 = (t[6] + t[14]) + t[22];
    float r7 = (t[7] + t[15]) + t[23];
    return ((r0 + r1) + (r2 + r3)) + ((r4 + r5) + (r6 + r7));
}

// ---------- rotated 3D IoU (mirrors reference _pair_iou3d in f32) ----------
__device__ float pair_iou3d(const float a[7], const float* __restrict__ b) {
    float oh = fminf(a[2] + a[5] * 0.5f, b[2] + b[5] * 0.5f)
             - fmaxf(a[2] - a[5] * 0.5f, b[2] - b[5] * 0.5f);
    oh = fmaxf(oh, 0.0f);
    float va = a[3] * a[4] * a[5];
    float vb = b[3] * b[4] * b[5];
    // conservative circle reject: reference yields exact 0.0 in these cases too
    float dx = a[0] - b[0], dy = a[1] - b[1];
    float ra = 0.5f * sqrtf(a[3] * a[3] + a[4] * a[4]);
    float rb = 0.5f * sqrtf(b[3] * b[3] + b[4] * b[4]);
    float rr = ra + rb + 1e-2f;
    if (oh <= 0.0f || (dx * dx + dy * dy) > rr * rr) return 0.0f;

    float ca = cosf(a[6]), sa = sinf(a[6]);
    float cb = cosf(b[6]), sb = sinf(b[6]);
    float axp[4], ayp[4], bxp[4], byp[4];
    {
        const float SX[4] = {1.f, 1.f, -1.f, -1.f};
        const float SY[4] = {1.f, -1.f, -1.f, 1.f};
        float hx = a[3] * 0.5f, hy = a[4] * 0.5f;
        for (int kk = 0; kk < 4; kk++) {
            float lx = SX[kk] * hx, ly = SY[kk] * hy;
            axp[kk] = lx * ca - ly * sa + a[0];
            ayp[kk] = lx * sa + ly * ca + a[1];
        }
        hx = b[3] * 0.5f; hy = b[4] * 0.5f;
        for (int kk = 0; kk < 4; kk++) {
            float lx = SX[kk] * hx, ly = SY[kk] * hy;
            bxp[kk] = lx * cb - ly * sb + b[0];
            byp[kk] = lx * sb + ly * cb + b[1];
        }
    }

    // candidate points at FIXED positions 0..23 (16 crossings i-major, 4 a-corners, 4 b-corners)
    float vx[24], vy[24];
    bool  mk[24];
    for (int i = 0; i < 4; i++) {
        float a1x = axp[i], a1y = ayp[i];
        float d1x = axp[(i + 1) & 3] - a1x, d1y = ayp[(i + 1) & 3] - a1y;
        for (int j = 0; j < 4; j++) {
            int pos = i * 4 + j;
            float b1x = bxp[j], b1y = byp[j];
            float d2x = bxp[(j + 1) & 3] - b1x, d2y = byp[(j + 1) & 3] - b1y;
            float fx = b1x - a1x, fy = b1y - a1y;
            float den = d1x * d2y - d1y * d2x;
            bool val = false;
            float px = 0.f, py = 0.f;
            if (fabsf(den) > 1e-8f) {
                float tt = (fx * d2y - fy * d2x) / den;
                float uu = (fx * d1y - fy * d1x) / den;
                if (tt >= 0.f && tt <= 1.f && uu >= 0.f && uu <= 1.f) {
                    val = true;
                    px = a1x + tt * d1x;
                    py = a1y + tt * d1y;
                }
            }
            mk[pos] = val; vx[pos] = px; vy[pos] = py;
        }
    }
    for (int kk = 0; kk < 4; kk++) {
        float rx = axp[kk] - b[0], ry = ayp[kk] - b[1];
        float lx = rx * cb + ry * sb, ly = -rx * sb + ry * cb;
        bool v = (fabsf(lx) <= b[3] * 0.5f + 1e-6f) && (fabsf(ly) <= b[4] * 0.5f + 1e-6f);
        mk[16 + kk] = v; vx[16 + kk] = v ? axp[kk] : 0.f; vy[16 + kk] = v ? ayp[kk] : 0.f;
    }
    for (int kk = 0; kk < 4; kk++) {
        float rx = bxp[kk] - a[0], ry = byp[kk] - a[1];
        float lx = rx * ca + ry * sa, ly = -rx * sa + ry * ca;
        bool v = (fabsf(lx) <= a[3] * 0.5f + 1e-6f) && (fabsf(ly) <= a[4] * 0.5f + 1e-6f);
        mk[20 + kk] = v; vx[20 + kk] = v ? bxp[kk] : 0.f; vy[20 + kk] = v ? byp[kk] : 0.f;
    }

    int nv = 0;
    for (int i = 0; i < 24; i++) nv += mk[i] ? 1 : 0;

    float area = 0.0f;
    if (nv > 0) {
        // ctr = (pts*m).sum(0)/max(nv,1): numpy blocked pairwise over 24 positional terms
        float cx = np_pw24(vx) / (float)nv;
        float cy = np_pw24(vy) / (float)nv;
        // valid vertices in candidate order (stable), angles
        float rx[24], ry[24], an[24];
        int k = 0;
        for (int i = 0; i < 24; i++) {
            if (mk[i]) {
                rx[k] = vx[i] - cx;
                ry[k] = vy[i] - cy;
                an[k] = atan2f(ry[k], rx[k]);
                k++;
            }
        }
        // stable insertion sort by angle
        int ord[24];
        for (int i = 0; i < k; i++) ord[i] = i;
        for (int i = 1; i < k; i++) {
            int oi = ord[i]; float ai = an[oi];
            int j = i - 1;
            while (j >= 0 && an[ord[j]] > ai) { ord[j + 1] = ord[j]; j--; }
            ord[j + 1] = oi;
        }
        // shoelace terms at sorted positions, invalid tail duplicates vertex0 (zero terms)
        float st[24];
        int c0 = ord[0];
        for (int i = 0; i < 24; i++) {
            int vi = (i < k) ? ord[i] : c0;
            int vn = (i + 1 < 24) ? ((i + 1 < k) ? ord[i + 1] : c0) : c0;
            st[i] = rx[vi] * ry[vn] - ry[vi] * rx[vn];
        }
        area = 0.5f * fabsf(np_pw24(st));
    }
    float inter = area * oh;
    return inter / fmaxf(va + vb - inter, 1e-6f);
}

// ---------- fused kernel: IoU + max/argmax + sampling + gather (f32 outputs) ----------
#define O_ROIS 0
#define O_GT   7168
#define O_IOU  15360
#define O_SC   16384
#define O_LB   17408
#define O_CLS  18432
#define O_REG  19456

__global__ __launch_bounds__(1024) void rcnn_fused(
    const float* __restrict__ rois, const float* __restrict__ gts,
    const float* __restrict__ scores, const int* __restrict__ labels,
    float* __restrict__ out)
{
    int b = blockIdx.x;
    int t = threadIdx.x;
    int lane = t & 63, wid = t >> 6;

    __shared__ float s_gt[NGT * 8];
    __shared__ int   s_last;
    __shared__ float s_mo[NM];
    __shared__ int   s_as[NM];
    __shared__ float s_ufg[NM];
    __shared__ int   s_fgc[NM];
    __shared__ int   s_hardc[NM];
    __shared__ int   s_easyc[NM];
    __shared__ int   s_perm[NM];
    __shared__ int   s_wcf[16], s_wch[16], s_wce[16];
    __shared__ int   s_nfg, s_nhard, s_neasy;

    // ---- stage 1: gt tile to LDS, last nonzero row ----
    if (t == 0) s_last = -1;
    for (int i = t; i < NGT * 8; i += 1024) s_gt[i] = gts[(size_t)b * NGT * 8 + i];
    __syncthreads();
    if (t < NGT) {
        float s8 = 0.f;
        for (int i = 0; i < 8; i++) s8 += s_gt[t * 8 + i];
        if (s8 != 0.f) atomicMax(&s_last, t);
    }
    __syncthreads();
    int last = s_last;

    // ---- stage 2: per-roi max/argmax IoU (first-max wins) ----
    float a[7];
    {
        const float* ap = rois + ((size_t)b * NM + t) * 7;
        for (int i = 0; i < 7; i++) a[i] = ap[i];
    }
    float best = -1.0f; int bi = 0;
    for (int g = 0; g <= last; g++) {
        float v = pair_iou3d(a, &s_gt[g * 8]);
        if (v > best) { best = v; bi = g; }
    }
    s_mo[t] = best;
    s_as[t] = bi;

    float mv = best;
    bool fg   = (mv >= 0.55f);
    bool easy = (mv < 0.1f);
    bool hard = (mv < 0.55f) && (mv >= 0.1f);

    u32 kk[4][2];
    image_keys(b, kk);
    float u1 = unif_at(kk[0], t);   // uniform(k1, (1024,))[t]

    // ---- stage 3: stable compaction of fg / hard / easy ----
    u64 lm  = (1ull << lane) - 1ull;
    u64 bf_ = __ballot(fg);
    u64 bh_ = __ballot(hard);
    u64 be_ = __ballot(easy);
    if (lane == 0) {
        s_wcf[wid] = __popcll(bf_);
        s_wch[wid] = __popcll(bh_);
        s_wce[wid] = __popcll(be_);
    }
    __syncthreads();
    if (t == 0) {
        int af = 0, ah = 0, ae = 0;
        for (int w = 0; w < 16; w++) {
            int cf = s_wcf[w], ch = s_wch[w], ce = s_wce[w];
            s_wcf[w] = af; s_wch[w] = ah; s_wce[w] = ae;
            af += cf; ah += ch; ae += ce;
        }
        s_nfg = af; s_nhard = ah; s_neasy = ae;
    }
    __syncthreads();
    if (fg)   { int p = s_wcf[wid] + __popcll(bf_ & lm); s_fgc[p] = t; s_ufg[p] = u1; }
    if (hard) { int p = s_wch[wid] + __popcll(bh_ & lm); s_hardc[p] = t; }
    if (easy) { int p = s_wce[wid] + __popcll(be_ & lm); s_easyc[p] = t; }
    __syncthreads();

    int n_fg = s_nfg, n_hard = s_nhard, n_easy = s_neasy;

    // fg_perm: fg indices stable-sorted by u1 (O(n_fg^2) rank)
    if (t < n_fg) {
        float ut = s_ufg[t];
        int r = 0;
        for (int j = 0; j < n_fg; j++) {
            float uj = s_ufg[j];
            r += (uj < ut) || (uj == ut && j < t);
        }
        s_perm[r] = s_fgc[t];
    }
    __syncthreads();

    // ---- stage 4: sample 128, gather, write f32 outputs ----
    if (t < 128) {
        int j = t;
        int n_bg = n_hard + n_easy;
        int fg_this = (n_fg > 0) ? ((n_bg > 0) ? ((n_fg < 64) ? n_fg : 64) : 128) : 0;
        int bg_this = 128 - fg_this;

        int idx;
        if (j < fg_this) {
            if (n_bg > 0) {
                idx = s_perm[j];
            } else {
                float u2 = unif_at(kk[1], j);
                int v = (int)(u2 * (float)n_fg);
                if (v > n_fg - 1) v = n_fg - 1;
                if (v < 0) v = 0;
                idx = s_fgc[v];
            }
        } else {
            int hard_num;
            if (n_hard > 0 && n_easy > 0) hard_num = (int)((float)bg_this * 0.8f);
            else hard_num = (n_hard > 0) ? bg_this : 0;
            if (j - fg_this < hard_num) {
                float u3 = unif_at(kk[2], j);
                int v = (int)(u3 * (float)n_hard);
                if (v > n_hard - 1) v = n_hard - 1;
                if (v < 0) v = 0;
                idx = s_hardc[v];
            } else {
                if (n_easy > 0) {
                    float u4 = unif_at(kk[3], j);
                    int v = (int)(u4 * (float)n_easy);
                    if (v > n_easy - 1) v = n_easy - 1;
                    if (v < 0) v = 0;
                    idx = s_easyc[v];
                } else {
                    idx = 0;
                }
            }
        }
        if (idx < 0) idx = 0;
        if (idx > NM - 1) idx = NM - 1;

        float moj = s_mo[idx];
        int g = s_as[idx];
        if (g < 0) g = 0;
        if (g > NGT - 1) g = NGT - 1;

        size_t base = (size_t)b * 128 + j;
        const float* rp = rois + ((size_t)b * NM + idx) * 7;
        float* orp = out + O_ROIS + base * 7;
        for (int i = 0; i < 7; i++) orp[i] = rp[i];            // exact f32 gather

        float* ogp = out + O_GT + base * 8;
        for (int i = 0; i < 8; i++) ogp[i] = s_gt[g * 8 + i];  // exact f32 gather

        out[O_IOU + base] = moj;
        out[O_SC + base]  = scores[(size_t)b * NM + idx];
        out[O_LB + base]  = (float)labels[(size_t)b * NM + idx];

        bool cfg = moj > 0.75f, cbg = moj < 0.25f;
        float cls = (!cfg && !cbg) ? (moj * 2.0f - 0.5f) : (cfg ? 1.0f : 0.0f);
        out[O_CLS + base] = cls;
        out[O_REG + base] = (moj > 0.55f) ? 1.0f : 0.0f;
    }
}

extern "C" void kernel_launch(void* const* d_in, const int* in_sizes, int n_in,
                              void* d_out, int out_size, void* d_ws, size_t ws_size,
                              hipStream_t stream) {
    // identify inputs by element count (scores/labels tie resolved in dict order)
    const float* rois   = nullptr;
    const float* gts    = nullptr;
    const float* scores = nullptr;
    const int*   labels = nullptr;
    for (int i = 0; i < n_in; i++) {
        if (in_sizes[i] == NB * NM * 7)       rois = (const float*)d_in[i];
        else if (in_sizes[i] == NB * NGT * 8) gts  = (const float*)d_in[i];
        else if (in_sizes[i] == NB * NM) {
            if (!scores) scores = (const float*)d_in[i];
            else         labels = (const int*)d_in[i];
        }
    }
    float* out = (float*)d_out;  // 20480 f32, outputs concatenated in return order

    rcnn_fused<<<NB, 1024, 0, stream>>>(rois, gts, scores, labels, out);
}

// Round 6
// 112.990 us; speedup vs baseline: 8.2773x; 8.2773x over previous
//
#include <hip/hip_runtime.h>
#include <stdint.h>

#pragma clang fp contract(off)

#define NB   8
#define NM   1024
#define NGT  100

typedef uint32_t u32;
typedef unsigned long long u64;

// ---------- Threefry-2x32 block (exact JAX schedule) ----------
__device__ __forceinline__ void tf2x32(u32 k0, u32 k1, u32 x0, u32 x1, u32& o0, u32& o1) {
    u32 k2 = k0 ^ k1 ^ 0x1BD11BDAu;
#define TFR(r) { x0 += x1; x1 = (x1 << r) | (x1 >> (32 - r)); x1 ^= x0; }
    x0 += k0; x1 += k1;
    TFR(13) TFR(15) TFR(26) TFR(6)
    x0 += k1; x1 += k2 + 1u;
    TFR(17) TFR(29) TFR(16) TFR(24)
    x0 += k2; x1 += k0 + 2u;
    TFR(13) TFR(15) TFR(26) TFR(6)
    x0 += k0; x1 += k1 + 3u;
    TFR(17) TFR(29) TFR(16) TFR(24)
    x0 += k1; x1 += k2 + 4u;
    TFR(13) TFR(15) TFR(26) TFR(6)
    x0 += k2; x1 += k0 + 5u;
#undef TFR
    o0 = x0; o1 = x1;
}

// JAX partitionable threefry: split(key,n)[i] = (o0,o1) at x=(0,i);
// random_bits(key,32,(n,))[i] = o0 ^ o1 at x=(0,i)
__device__ __forceinline__ u32 tf_bits32(u32 k0, u32 k1, u32 i) {
    u32 o0, o1;
    tf2x32(k0, k1, 0u, i, o0, o1);
    return o0 ^ o1;
}

__device__ __forceinline__ float bits2unif(u32 bits) {
    return __uint_as_float((bits >> 9) | 0x3f800000u) - 1.0f;
}

__device__ __forceinline__ void image_keys(int b, u32 k[4][2]) {
    u32 kb0, kb1;
    tf2x32(0u, 42u, 0u, (u32)b, kb0, kb1);               // split(key(42), 8)[b]
    for (int i = 0; i < 4; i++)
        tf2x32(kb0, kb1, 0u, (u32)i, k[i][0], k[i][1]);  // split(key_b, 4)[i]
}

__device__ __forceinline__ float unif_at(const u32 k[2], int i) {
    return bits2unif(tf_bits32(k[0], k[1], (u32)i));
}

// ---------- numpy pairwise blocked sum over exactly 24 f32 terms ----------
__device__ __forceinline__ float np_pw24(const float* t) {
    float r0 = (t[0] + t[8])  + t[16];
    float r1 = (t[1] + t[9])  + t[17];
    float r2 = (t[2] + t[10]) + t[18];
    float r3 = (t[3] + t[11]) + t[19];
    float r4 = (t[4] + t[12]) + t[20];
    float r5 = (t[5] + t[13]) + t[21];
    float r6 = (t[6] + t[14]) + t[22];
    float r7 = (t[7] + t[15]) + t[23];
    return ((r0 + r1) + (r2 + r3)) + ((r4 + r5) + (r6 + r7));
}

// ---------- rotated 3D IoU (mirrors reference _pair_iou3d in f32) ----------
__device__ float pair_iou3d(const float a[7], const float* __restrict__ b) {
    float oh = fminf(a[2] + a[5] * 0.5f, b[2] + b[5] * 0.5f)
             - fmaxf(a[2] - a[5] * 0.5f, b[2] - b[5] * 0.5f);
    oh = fmaxf(oh, 0.0f);
    float va = a[3] * a[4] * a[5];
    float vb = b[3] * b[4] * b[5];
    // conservative circle reject: reference yields exact 0.0 in these cases too
    float dx = a[0] - b[0], dy = a[1] - b[1];
    float ra = 0.5f * sqrtf(a[3] * a[3] + a[4] * a[4]);
    float rb = 0.5f * sqrtf(b[3] * b[3] + b[4] * b[4]);
    float rr = ra + rb + 1e-2f;
    if (oh <= 0.0f || (dx * dx + dy * dy) > rr * rr) return 0.0f;

    float ca = cosf(a[6]), sa = sinf(a[6]);
    float cb = cosf(b[6]), sb = sinf(b[6]);
    float axp[4], ayp[4], bxp[4], byp[4];
    {
        const float SX[4] = {1.f, 1.f, -1.f, -1.f};
        const float SY[4] = {1.f, -1.f, -1.f, 1.f};
        float hx = a[3] * 0.5f, hy = a[4] * 0.5f;
        for (int kk = 0; kk < 4; kk++) {
            float lx = SX[kk] * hx, ly = SY[kk] * hy;
            axp[kk] = lx * ca - ly * sa + a[0];
            ayp[kk] = lx * sa + ly * ca + a[1];
        }
        hx = b[3] * 0.5f; hy = b[4] * 0.5f;
        for (int kk = 0; kk < 4; kk++) {
            float lx = SX[kk] * hx, ly = SY[kk] * hy;
            bxp[kk] = lx * cb - ly * sb + b[0];
            byp[kk] = lx * sb + ly * cb + b[1];
        }
    }

    // candidate points at FIXED positions 0..23 (16 crossings i-major, 4 a-corners, 4 b-corners)
    float vx[24], vy[24];
    bool  mk[24];
    for (int i = 0; i < 4; i++) {
        float a1x = axp[i], a1y = ayp[i];
        float d1x = axp[(i + 1) & 3] - a1x, d1y = ayp[(i + 1) & 3] - a1y;
        for (int j = 0; j < 4; j++) {
            int pos = i * 4 + j;
            float b1x = bxp[j], b1y = byp[j];
            float d2x = bxp[(j + 1) & 3] - b1x, d2y = byp[(j + 1) & 3] - b1y;
            float fx = b1x - a1x, fy = b1y - a1y;
            float den = d1x * d2y - d1y * d2x;
            bool val = false;
            float px = 0.f, py = 0.f;
            if (fabsf(den) > 1e-8f) {
                float tt = (fx * d2y - fy * d2x) / den;
                float uu = (fx * d1y - fy * d1x) / den;
                if (tt >= 0.f && tt <= 1.f && uu >= 0.f && uu <= 1.f) {
                    val = true;
                    px = a1x + tt * d1x;
                    py = a1y + tt * d1y;
                }
            }
            mk[pos] = val; vx[pos] = px; vy[pos] = py;
        }
    }
    for (int kk = 0; kk < 4; kk++) {
        float rx = axp[kk] - b[0], ry = ayp[kk] - b[1];
        float lx = rx * cb + ry * sb, ly = -rx * sb + ry * cb;
        bool v = (fabsf(lx) <= b[3] * 0.5f + 1e-6f) && (fabsf(ly) <= b[4] * 0.5f + 1e-6f);
        mk[16 + kk] = v; vx[16 + kk] = v ? axp[kk] : 0.f; vy[16 + kk] = v ? ayp[kk] : 0.f;
    }
    for (int kk = 0; kk < 4; kk++) {
        float rx = bxp[kk] - a[0], ry = byp[kk] - a[1];
        float lx = rx * ca + ry * sa, ly = -rx * sa + ry * ca;
        bool v = (fabsf(lx) <= a[3] * 0.5f + 1e-6f) && (fabsf(ly) <= a[4] * 0.5f + 1e-6f);
        mk[20 + kk] = v; vx[20 + kk] = v ? bxp[kk] : 0.f; vy[20 + kk] = v ? byp[kk] : 0.f;
    }

    int nv = 0;
    for (int i = 0; i < 24; i++) nv += mk[i] ? 1 : 0;

    float area = 0.0f;
    if (nv > 0) {
        float cx = np_pw24(vx) / (float)nv;
        float cy = np_pw24(vy) / (float)nv;
        float rx[24], ry[24], an[24];
        int k = 0;
        for (int i = 0; i < 24; i++) {
            if (mk[i]) {
                rx[k] = vx[i] - cx;
                ry[k] = vy[i] - cy;
                an[k] = atan2f(ry[k], rx[k]);
                k++;
            }
        }
        int ord[24];
        for (int i = 0; i < k; i++) ord[i] = i;
        for (int i = 1; i < k; i++) {
            int oi = ord[i]; float ai = an[oi];
            int j = i - 1;
            while (j >= 0 && an[ord[j]] > ai) { ord[j + 1] = ord[j]; j--; }
            ord[j + 1] = oi;
        }
        float st[24];
        int c0 = ord[0];
        for (int i = 0; i < 24; i++) {
            int vi = (i < k) ? ord[i] : c0;
            int vn = (i + 1 < 24) ? ((i + 1 < k) ? ord[i + 1] : c0) : c0;
            st[i] = rx[vi] * ry[vn] - ry[vi] * rx[vn];
        }
        area = 0.5f * fabsf(np_pw24(st));
    }
    float inter = area * oh;
    return inter / fmaxf(va + vb - inter, 1e-6f);
}

// ---------- kernel A: one wave per roi; lane g-split + shuffle argmax ----------
// block = 256 (4 waves -> 4 rois), grid = 8192/4 = 2048. 1024 % 4 == 0 so all
// 4 rois of a block share one image -> one LDS gt tile per block.
__global__ __launch_bounds__(256) void overlap_kernel(
    const float* __restrict__ rois, const float* __restrict__ gts,
    float* __restrict__ mo, int* __restrict__ asgn)
{
    int t = threadIdx.x;
    int lane = t & 63, wid = t >> 6;
    int r = blockIdx.x * 4 + wid;      // flat roi id in [0, 8192)
    int b = r >> 10;

    __shared__ float s_gt[NGT * 8];
    __shared__ int   s_last;

    if (t == 0) s_last = -1;
    for (int i = t; i < NGT * 8; i += 256) s_gt[i] = gts[(size_t)b * NGT * 8 + i];
    __syncthreads();
    if (t < NGT) {
        float s8 = 0.f;
        for (int i = 0; i < 8; i++) s8 += s_gt[t * 8 + i];
        if (s8 != 0.f) atomicMax(&s_last, t);
    }
    __syncthreads();
    int last = s_last;

    float a[7];
    {
        const float* ap = rois + (size_t)r * 7;
        for (int i = 0; i < 7; i++) a[i] = ap[i];
    }

    // lane covers g = lane and g = lane + 64 (both masked to -1 beyond `last`)
    float v0 = (lane <= last) ? pair_iou3d(a, &s_gt[lane * 8]) : -1.0f;
    int   g1 = lane + 64;
    float v1 = (g1 <= last)   ? pair_iou3d(a, &s_gt[g1 * 8])   : -1.0f;

    float bv; int bi;
    if (v1 > v0) { bv = v1; bi = g1; } else { bv = v0; bi = lane; }  // tie -> smaller g

    // wave max/argmax, first-index-wins (matches jnp.argmax)
    for (int s = 32; s > 0; s >>= 1) {
        float v2 = __shfl_down(bv, s);
        int   i2 = __shfl_down(bi, s);
        if (v2 > bv || (v2 == bv && i2 < bi)) { bv = v2; bi = i2; }
    }
    if (lane == 0) {
        mo[r]   = bv;
        asgn[r] = bi;
    }
}

// ---------- kernel B: per-image sampling + gather (f32 outputs) ----------
#define O_ROIS 0
#define O_GT   7168
#define O_IOU  15360
#define O_SC   16384
#define O_LB   17408
#define O_CLS  18432
#define O_REG  19456

__global__ __launch_bounds__(1024) void sample_kernel(
    const float* __restrict__ rois, const float* __restrict__ gts,
    const float* __restrict__ scores, const int* __restrict__ labels,
    const float* __restrict__ mo, const int* __restrict__ asgn,
    float* __restrict__ out)
{
    int b = blockIdx.x;
    int t = threadIdx.x;
    int lane = t & 63, wid = t >> 6;

    __shared__ float s_mo[NM];
    __shared__ float s_ufg[NM];
    __shared__ int   s_fgc[NM];
    __shared__ int   s_hardc[NM];
    __shared__ int   s_easyc[NM];
    __shared__ int   s_perm[NM];
    __shared__ int   s_wcf[16], s_wch[16], s_wce[16];
    __shared__ int   s_nfg, s_nhard, s_neasy;

    u32 kk[4][2];
    image_keys(b, kk);

    float mv = mo[(size_t)b * NM + t];
    s_mo[t] = mv;
    bool fg   = (mv >= 0.55f);
    bool easy = (mv < 0.1f);
    bool hard = (mv < 0.55f) && (mv >= 0.1f);

    float u1 = unif_at(kk[0], t);   // uniform(k1, (1024,))[t]

    u64 lm  = (1ull << lane) - 1ull;
    u64 bf_ = __ballot(fg);
    u64 bh_ = __ballot(hard);
    u64 be_ = __ballot(easy);
    if (lane == 0) {
        s_wcf[wid] = __popcll(bf_);
        s_wch[wid] = __popcll(bh_);
        s_wce[wid] = __popcll(be_);
    }
    __syncthreads();
    if (t == 0) {
        int af = 0, ah = 0, ae = 0;
        for (int w = 0; w < 16; w++) {
            int cf = s_wcf[w], ch = s_wch[w], ce = s_wce[w];
            s_wcf[w] = af; s_wch[w] = ah; s_wce[w] = ae;
            af += cf; ah += ch; ae += ce;
        }
        s_nfg = af; s_nhard = ah; s_neasy = ae;
    }
    __syncthreads();
    if (fg)   { int p = s_wcf[wid] + __popcll(bf_ & lm); s_fgc[p] = t; s_ufg[p] = u1; }
    if (hard) { int p = s_wch[wid] + __popcll(bh_ & lm); s_hardc[p] = t; }
    if (easy) { int p = s_wce[wid] + __popcll(be_ & lm); s_easyc[p] = t; }
    __syncthreads();

    int n_fg = s_nfg, n_hard = s_nhard, n_easy = s_neasy;

    // fg_perm: fg indices stable-sorted by u1 (O(n_fg^2) rank)
    if (t < n_fg) {
        float ut = s_ufg[t];
        int r = 0;
        for (int j = 0; j < n_fg; j++) {
            float uj = s_ufg[j];
            r += (uj < ut) || (uj == ut && j < t);
        }
        s_perm[r] = s_fgc[t];
    }
    __syncthreads();

    if (t < 128) {
        int j = t;
        int n_bg = n_hard + n_easy;
        int fg_this = (n_fg > 0) ? ((n_bg > 0) ? ((n_fg < 64) ? n_fg : 64) : 128) : 0;
        int bg_this = 128 - fg_this;

        int idx;
        if (j < fg_this) {
            if (n_bg > 0) {
                idx = s_perm[j];
            } else {
                float u2 = unif_at(kk[1], j);
                int v = (int)(u2 * (float)n_fg);
                if (v > n_fg - 1) v = n_fg - 1;
                if (v < 0) v = 0;
                idx = s_fgc[v];
            }
        } else {
            int hard_num;
            if (n_hard > 0 && n_easy > 0) hard_num = (int)((float)bg_this * 0.8f);
            else hard_num = (n_hard > 0) ? bg_this : 0;
            if (j - fg_this < hard_num) {
                float u3 = unif_at(kk[2], j);
                int v = (int)(u3 * (float)n_hard);
                if (v > n_hard - 1) v = n_hard - 1;
                if (v < 0) v = 0;
                idx = s_hardc[v];
            } else {
                if (n_easy > 0) {
                    float u4 = unif_at(kk[3], j);
                    int v = (int)(u4 * (float)n_easy);
                    if (v > n_easy - 1) v = n_easy - 1;
                    if (v < 0) v = 0;
                    idx = s_easyc[v];
                } else {
                    idx = 0;
                }
            }
        }
        if (idx < 0) idx = 0;
        if (idx > NM - 1) idx = NM - 1;

        float moj = s_mo[idx];
        int g = asgn[(size_t)b * NM + idx];
        if (g < 0) g = 0;
        if (g > NGT - 1) g = NGT - 1;

        size_t base = (size_t)b * 128 + j;
        const float* rp = rois + ((size_t)b * NM + idx) * 7;
        float* orp = out + O_ROIS + base * 7;
        for (int i = 0; i < 7; i++) orp[i] = rp[i];                       // exact f32 gather

        const float* gp = gts + ((size_t)b * NGT + g) * 8;
        float* ogp = out + O_GT + base * 8;
        for (int i = 0; i < 8; i++) ogp[i] = gp[i];                       // exact f32 gather

        out[O_IOU + base] = moj;
        out[O_SC + base]  = scores[(size_t)b * NM + idx];
        out[O_LB + base]  = (float)labels[(size_t)b * NM + idx];

        bool cfg = moj > 0.75f, cbg = moj < 0.25f;
        float cls = (!cfg && !cbg) ? (moj * 2.0f - 0.5f) : (cfg ? 1.0f : 0.0f);
        out[O_CLS + base] = cls;
        out[O_REG + base] = (moj > 0.55f) ? 1.0f : 0.0f;
    }
}

extern "C" void kernel_launch(void* const* d_in, const int* in_sizes, int n_in,
                              void* d_out, int out_size, void* d_ws, size_t ws_size,
                              hipStream_t stream) {
    // identify inputs by element count (scores/labels tie resolved in dict order)
    const float* rois   = nullptr;
    const float* gts    = nullptr;
    const float* scores = nullptr;
    const int*   labels = nullptr;
    for (int i = 0; i < n_in; i++) {
        if (in_sizes[i] == NB * NM * 7)       rois = (const float*)d_in[i];
        else if (in_sizes[i] == NB * NGT * 8) gts  = (const float*)d_in[i];
        else if (in_sizes[i] == NB * NM) {
            if (!scores) scores = (const float*)d_in[i];
            else         labels = (const int*)d_in[i];
        }
    }
    float* out = (float*)d_out;  // 20480 f32, outputs concatenated in return order

    float* mo  = (float*)d_ws;                                   // 8192 f32
    int*   asg = (int*)((char*)d_ws + NB * NM * sizeof(float));  // 8192 i32

    overlap_kernel<<<NB * NM / 4, 256, 0, stream>>>(rois, gts, mo, asg);
    sample_kernel<<<NB, 1024, 0, stream>>>(rois, gts, scores, labels, mo, asg, out);
}